// Round 3
// baseline (447.916 us; speedup 1.0000x reference)
//
#include <hip/hip_runtime.h>
#include <cstdint>

typedef float  f32x4  __attribute__((ext_vector_type(4)));
typedef short  short8 __attribute__((ext_vector_type(8)));
typedef _Float16 half4 __attribute__((ext_vector_type(4)));

// ---------- helpers ----------
__device__ __forceinline__ unsigned short f2bf(float f) {
    unsigned u = __builtin_bit_cast(unsigned, f);
    u += 0x7FFFu + ((u >> 16) & 1u);   // RNE
    return (unsigned short)(u >> 16);
}

// ---------- kernel 1: weights fp32 -> bf16 (3 x 256 x 256) ----------
__global__ void wconv_kernel(const float* __restrict__ wq,
                             const float* __restrict__ wk,
                             const float* __restrict__ wv,
                             unsigned short* __restrict__ Wb) {
    int p = blockIdx.x >> 8;                       // 0..2
    int i = ((blockIdx.x & 255) << 8) + threadIdx.x; // 0..65535
    const float* src = (p == 0) ? wq : ((p == 1) ? wk : wv);
    Wb[(p << 16) + i] = f2bf(src[i]);
}

// ---------- kernel 2: build X0 [B][S][256] bf16 ----------
__global__ void build_x0_kernel(const float* __restrict__ x,
                                unsigned short* __restrict__ X0) {
    __shared__ float tile[32][33];
    int b  = blockIdx.z;
    int ct = blockIdx.y;     // 0..7  (32 channels each)
    int st = blockIdx.x;     // 0..31 (32 s each)
    int tid = threadIdx.x;
    int lo = tid & 31, hi = tid >> 5;   // 8 rows per pass

    if (ct < 7) {
        #pragma unroll
        for (int r = 0; r < 4; ++r) {
            int c = hi + 8 * r;
            tile[c][lo] = x[((b * 224 + ct * 32 + c) << 10) + st * 32 + lo];
        }
        __syncthreads();
        #pragma unroll
        for (int r = 0; r < 4; ++r) {
            int s_loc = hi + 8 * r;
            X0[(((b << 10) + st * 32 + s_loc) << 8) + ct * 32 + lo] = f2bf(tile[lo][s_loc]);
        }
    } else {
        #pragma unroll
        for (int r = 0; r < 4; ++r) {
            int s_loc = hi + 8 * r;
            int s = st * 32 + s_loc;
            int h = s >> 5, w = s & 31;
            int ch = lo;  // 0..31 -> pe channel
            int i = (ch < 16) ? (ch * 32 + h) : ((ch - 16) * 32 + w);
            int l = i >> 4, e = i & 15;
            float val = 0.f;
            if (l > 0) {
                float ang = (float)l * powf(10000.f, -(float)(e >> 1) * 0.125f);
                val = (e & 1) ? cosf(ang) : sinf(ang);
            }
            X0[(((b << 10) + s) << 8) + 224 + ch] = f2bf(val);
        }
    }
}

// ---------- kernel 3: QKV projection ----------
__global__ __launch_bounds__(256) void proj_kernel(
        const unsigned short* __restrict__ X0,
        const unsigned short* __restrict__ Wb,
        const float* __restrict__ bq, const float* __restrict__ bk,
        const float* __restrict__ bv,
        unsigned short* __restrict__ Q, unsigned short* __restrict__ K,
        _Float16* __restrict__ V) {
    int pb = blockIdx.z; int proj = pb >> 5; int b = pb & 31;
    int tid = threadIdx.x; int w = tid >> 6; int l = tid & 63;
    int g = l >> 4, c = l & 15;
    int s0 = blockIdx.x * 64 + w * 16;
    int o0 = blockIdx.y * 64;
    const unsigned short* Wp = Wb + (proj << 16);
    const float* bias = (proj == 0) ? bq : ((proj == 1) ? bk : bv);

    f32x4 acc[4];
    #pragma unroll
    for (int ot = 0; ot < 4; ++ot) acc[ot] = (f32x4){0.f, 0.f, 0.f, 0.f};

    const short8* arow = (const short8*)&X0[(((b << 10) + s0 + c) << 8)];
    #pragma unroll
    for (int kk = 0; kk < 8; ++kk) {
        short8 a = arow[kk * 4 + g];     // d = kk*32 + 8g .. +7
        #pragma unroll
        for (int ot = 0; ot < 4; ++ot) {
            short8 bfr = *(const short8*)&Wp[(o0 + ot * 16 + c) * 256 + kk * 32 + g * 8];
            acc[ot] = __builtin_amdgcn_mfma_f32_16x16x32_bf16(a, bfr, acc[ot], 0, 0, 0);
        }
    }

    #pragma unroll
    for (int ot = 0; ot < 4; ++ot) {
        int o = o0 + ot * 16 + c;
        float bb = bias[o];
        if (proj < 2) {
            unsigned short* dst = (proj == 0) ? Q : K;
            #pragma unroll
            for (int r = 0; r < 4; ++r) {
                float v = fmaxf(acc[ot][r] + bb, 0.f);
                int s = s0 + 4 * g + r;
                dst[(((b << 10) + s) << 8) + o] = f2bf(v);
            }
        } else {
            half4 hv;
            #pragma unroll
            for (int r = 0; r < 4; ++r)
                hv[r] = (_Float16)fmaxf(acc[ot][r] + bb, 0.f);
            *(half4*)&V[(((b << 8) + o) << 10) + s0 + 4 * g] = hv;
        }
    }
}

// ---------- kernel 4: causal attention ----------
// 1024 blocks x 512 threads. 8 waves = {slot qt in {a,63-a}} x {t-parity} x {v-half}.
// Per-wave: qf 32 regs + acc[8] 32 regs -> fits 128-reg cap, no spill.
__global__ __launch_bounds__(512, 4) void attn_kernel(
        const unsigned short* __restrict__ Q,
        const unsigned short* __restrict__ K,
        const _Float16* __restrict__ V,
        float* __restrict__ out) {
    __shared__ float lacc[2][2][16][132];   // [slot][vhalf][c][vt*16+4g+r]
    __shared__ float lml[2][2][2][16];      // [slot][vhalf][{m,l}][c]

    int bid = blockIdx.x;
    int xcd = bid & 7;
    int j   = bid >> 3;                 // 0..127
    int b   = ((j >> 5) << 3) | xcd;    // batches grouped per XCD for L2 locality
    int a   = j & 31;

    int tid = threadIdx.x;
    int w8 = tid >> 6; int l = tid & 63;
    int g = l >> 4, c = l & 15;
    int vhalf  = w8 & 1;
    int parity = (w8 >> 1) & 1;
    int slot   = ((w8 >> 2) + bid) & 1;   // rotate long/short across blocks
    int qt = slot ? (63 - a) : a;
    int s0 = qt << 4;

    short8 qf[8];
    #pragma unroll
    for (int kk = 0; kk < 8; ++kk)
        qf[kk] = *(const short8*)&Q[(((b << 10) + s0 + c) << 8) + kk * 32 + g * 8];

    float m = -1e30f, lsum = 0.f;
    f32x4 acc[8];
    #pragma unroll
    for (int i = 0; i < 8; ++i) acc[i] = (f32x4){0.f, 0.f, 0.f, 0.f};

    for (int tt = parity; tt <= qt; tt += 2) {
        int t0 = tt << 4;
        f32x4 sc0 = (f32x4){0.f, 0.f, 0.f, 0.f};
        f32x4 sc1 = (f32x4){0.f, 0.f, 0.f, 0.f};
        __builtin_amdgcn_s_setprio(1);
        #pragma unroll
        for (int kk = 0; kk < 8; kk += 2) {
            short8 af0 = *(const short8*)&K[(((b << 10) + t0 + c) << 8) + kk * 32 + g * 8];
            short8 af1 = *(const short8*)&K[(((b << 10) + t0 + c) << 8) + (kk + 1) * 32 + g * 8];
            sc0 = __builtin_amdgcn_mfma_f32_16x16x32_bf16(af0, qf[kk], sc0, 0, 0, 0);
            sc1 = __builtin_amdgcn_mfma_f32_16x16x32_bf16(af1, qf[kk + 1], sc1, 0, 0, 0);
        }
        __builtin_amdgcn_s_setprio(0);
        float sv[4];
        #pragma unroll
        for (int r = 0; r < 4; ++r) sv[r] = (sc0[r] + sc1[r]) * 0.0625f;
        if (tt == qt) {   // diagonal tile: mask t > s
            #pragma unroll
            for (int r = 0; r < 4; ++r)
                if (4 * g + r > c) sv[r] = -1e30f;
        }
        float tm = fmaxf(fmaxf(sv[0], sv[1]), fmaxf(sv[2], sv[3]));
        tm = fmaxf(tm, __shfl_xor(tm, 16));
        tm = fmaxf(tm, __shfl_xor(tm, 32));
        // T13 defer-max: only rescale when the running max grows materially
        if (!__all((int)(tm <= m + 8.f))) {
            float mnew = fmaxf(m, tm);
            float alpha = __expf(m - mnew);
            m = mnew;
            lsum *= alpha;
            #pragma unroll
            for (int i = 0; i < 8; ++i) acc[i] *= alpha;
        }
        float p[4]; float ps = 0.f;
        #pragma unroll
        for (int r = 0; r < 4; ++r) { p[r] = __expf(sv[r] - m); ps += p[r]; }
        ps += __shfl_xor(ps, 16);
        ps += __shfl_xor(ps, 32);
        lsum += ps;
        half4 pb;
        #pragma unroll
        for (int r = 0; r < 4; ++r) pb[r] = (_Float16)p[r];
        __builtin_amdgcn_s_setprio(1);
        #pragma unroll
        for (int vt = 0; vt < 8; ++vt) {
            half4 va = *(const half4*)&V[(((b << 8) + vhalf * 128 + vt * 16 + c) << 10) + t0 + 4 * g];
            acc[vt] = __builtin_amdgcn_mfma_f32_16x16x16f16(va, pb, acc[vt], 0, 0, 0);
        }
        __builtin_amdgcn_s_setprio(0);
    }

    // ---- flash combine across the two parity waves of each (slot, vhalf) ----
    if (parity == 0) {
        #pragma unroll
        for (int vt = 0; vt < 8; ++vt)
            *(f32x4*)&lacc[slot][vhalf][c][vt * 16 + 4 * g] = acc[vt];
        if (g == 0) { lml[slot][vhalf][0][c] = m; lml[slot][vhalf][1][c] = lsum; }
    }
    __syncthreads();
    if (parity == 1) {
        float mA = lml[slot][vhalf][0][c];
        float lA = lml[slot][vhalf][1][c];
        float ms = fmaxf(mA, m);
        float aA = __expf(mA - ms);
        float aB = __expf(m - ms);
        float rl = 1.f / (lA * aA + lsum * aB);
        #pragma unroll
        for (int vt = 0; vt < 8; ++vt) {
            f32x4 other = *(const f32x4*)&lacc[slot][vhalf][c][vt * 16 + 4 * g];
            #pragma unroll
            for (int r = 0; r < 4; ++r) {
                float val = (other[r] * aA + acc[vt][r] * aB) * rl;
                out[(((b << 8) + vhalf * 128 + vt * 16 + 4 * g + r) << 10) + s0 + c] = val;
            }
        }
    }
}

// ---------- launcher ----------
extern "C" void kernel_launch(void* const* d_in, const int* in_sizes, int n_in,
                              void* d_out, int out_size, void* d_ws, size_t ws_size,
                              hipStream_t stream) {
    const float* x  = (const float*)d_in[0];
    const float* wq = (const float*)d_in[1];
    const float* bq = (const float*)d_in[2];
    const float* wk = (const float*)d_in[3];
    const float* bk = (const float*)d_in[4];
    const float* wv = (const float*)d_in[5];
    const float* bv = (const float*)d_in[6];
    float* out = (float*)d_out;

    char* ws = (char*)d_ws;
    unsigned short* Wb = (unsigned short*)ws;                       // 393,216 B
    unsigned short* X0 = (unsigned short*)(ws + 393216);            // 16,777,216 B
    unsigned short* Qb = (unsigned short*)(ws + 393216 + 16777216);
    unsigned short* Kb = (unsigned short*)(ws + 393216 + 2 * 16777216);
    _Float16*       Vb = (_Float16*)     (ws + 393216 + 3 * 16777216);

    wconv_kernel<<<768, 256, 0, stream>>>(wq, wk, wv, Wb);
    build_x0_kernel<<<dim3(32, 8, 32), 256, 0, stream>>>(x, X0);
    proj_kernel<<<dim3(16, 4, 96), 256, 0, stream>>>(X0, Wb, bq, bk, bv, Qb, Kb, Vb);
    attn_kernel<<<1024, 512, 0, stream>>>(Qb, Kb, Vb, out);
}

// Round 4
// 314.948 us; speedup vs baseline: 1.4222x; 1.4222x over previous
//
#include <hip/hip_runtime.h>
#include <cstdint>

typedef float  f32x4  __attribute__((ext_vector_type(4)));
typedef short  short8 __attribute__((ext_vector_type(8)));
typedef _Float16 half4 __attribute__((ext_vector_type(4)));

// ---------- helpers ----------
__device__ __forceinline__ unsigned short f2bf(float f) {
    unsigned u = __builtin_bit_cast(unsigned, f);
    u += 0x7FFFu + ((u >> 16) & 1u);   // RNE
    return (unsigned short)(u >> 16);
}

// ---------- kernel 1: weights fp32 -> bf16 (3 x 256 x 256) ----------
__global__ void wconv_kernel(const float* __restrict__ wq,
                             const float* __restrict__ wk,
                             const float* __restrict__ wv,
                             unsigned short* __restrict__ Wb) {
    int p = blockIdx.x >> 8;                       // 0..2
    int i = ((blockIdx.x & 255) << 8) + threadIdx.x; // 0..65535
    const float* src = (p == 0) ? wq : ((p == 1) ? wk : wv);
    Wb[(p << 16) + i] = f2bf(src[i]);
}

// ---------- kernel 2: build X0 [B][S][256] bf16 ----------
__global__ void build_x0_kernel(const float* __restrict__ x,
                                unsigned short* __restrict__ X0) {
    __shared__ float tile[32][33];
    int b  = blockIdx.z;
    int ct = blockIdx.y;     // 0..7  (32 channels each)
    int st = blockIdx.x;     // 0..31 (32 s each)
    int tid = threadIdx.x;
    int lo = tid & 31, hi = tid >> 5;   // 8 rows per pass

    if (ct < 7) {
        #pragma unroll
        for (int r = 0; r < 4; ++r) {
            int c = hi + 8 * r;
            tile[c][lo] = x[((b * 224 + ct * 32 + c) << 10) + st * 32 + lo];
        }
        __syncthreads();
        #pragma unroll
        for (int r = 0; r < 4; ++r) {
            int s_loc = hi + 8 * r;
            X0[(((b << 10) + st * 32 + s_loc) << 8) + ct * 32 + lo] = f2bf(tile[lo][s_loc]);
        }
    } else {
        #pragma unroll
        for (int r = 0; r < 4; ++r) {
            int s_loc = hi + 8 * r;
            int s = st * 32 + s_loc;
            int h = s >> 5, w = s & 31;
            int ch = lo;  // 0..31 -> pe channel
            int i = (ch < 16) ? (ch * 32 + h) : ((ch - 16) * 32 + w);
            int l = i >> 4, e = i & 15;
            float val = 0.f;
            if (l > 0) {
                float ang = (float)l * powf(10000.f, -(float)(e >> 1) * 0.125f);
                val = (e & 1) ? cosf(ang) : sinf(ang);
            }
            X0[(((b << 10) + s) << 8) + 224 + ch] = f2bf(val);
        }
    }
}

// ---------- kernel 3: QKV projection ----------
__global__ __launch_bounds__(256) void proj_kernel(
        const unsigned short* __restrict__ X0,
        const unsigned short* __restrict__ Wb,
        const float* __restrict__ bq, const float* __restrict__ bk,
        const float* __restrict__ bv,
        unsigned short* __restrict__ Q, unsigned short* __restrict__ K,
        _Float16* __restrict__ V) {
    int pb = blockIdx.z; int proj = pb >> 5; int b = pb & 31;
    int tid = threadIdx.x; int w = tid >> 6; int l = tid & 63;
    int g = l >> 4, c = l & 15;
    int s0 = blockIdx.x * 64 + w * 16;
    int o0 = blockIdx.y * 64;
    const unsigned short* Wp = Wb + (proj << 16);
    const float* bias = (proj == 0) ? bq : ((proj == 1) ? bk : bv);

    f32x4 acc[4];
    #pragma unroll
    for (int ot = 0; ot < 4; ++ot) acc[ot] = (f32x4){0.f, 0.f, 0.f, 0.f};

    const short8* arow = (const short8*)&X0[(((b << 10) + s0 + c) << 8)];
    #pragma unroll
    for (int kk = 0; kk < 8; ++kk) {
        short8 a = arow[kk * 4 + g];     // d = kk*32 + 8g .. +7
        #pragma unroll
        for (int ot = 0; ot < 4; ++ot) {
            short8 bfr = *(const short8*)&Wp[(o0 + ot * 16 + c) * 256 + kk * 32 + g * 8];
            acc[ot] = __builtin_amdgcn_mfma_f32_16x16x32_bf16(a, bfr, acc[ot], 0, 0, 0);
        }
    }

    #pragma unroll
    for (int ot = 0; ot < 4; ++ot) {
        int o = o0 + ot * 16 + c;
        float bb = bias[o];
        if (proj < 2) {
            unsigned short* dst = (proj == 0) ? Q : K;
            #pragma unroll
            for (int r = 0; r < 4; ++r) {
                float v = fmaxf(acc[ot][r] + bb, 0.f);
                int s = s0 + 4 * g + r;
                dst[(((b << 10) + s) << 8) + o] = f2bf(v);
            }
        } else {
            half4 hv;
            #pragma unroll
            for (int r = 0; r < 4; ++r)
                hv[r] = (_Float16)fmaxf(acc[ot][r] + bb, 0.f);
            *(half4*)&V[(((b << 8) + o) << 10) + s0 + 4 * g] = hv;
        }
    }
}

// ---------- kernel 4: causal attention ----------
// 1024 blocks x 256 threads (4 waves). Block = (batch XCD-grouped, a).
// Waves: slot (qt = a or 63-a) x parity (t-tiles mod 2, processed in PAIRS).
// Per-wave regs ~200 (cap 256 via launch_bounds(256,2)) -> no spill.
__global__ __launch_bounds__(256, 2) void attn_kernel(
        const unsigned short* __restrict__ Q,
        const unsigned short* __restrict__ K,
        const _Float16* __restrict__ V,
        float* __restrict__ out) {
    __shared__ float lacc[2][16][260];   // [slot][c][vt*16+4g+r]  (~33 KB)
    __shared__ float lml[2][2][16];

    int bid = blockIdx.x;
    int xcd = bid & 7;
    int j   = bid >> 3;                 // 0..127
    int b   = ((j >> 5) << 3) | xcd;    // batches grouped per XCD (L2 locality)
    int a   = j & 31;

    int tid = threadIdx.x; int w = tid >> 6; int l = tid & 63;
    int g = l >> 4, c = l & 15;
    int slot = w >> 1, parity = w & 1;
    int qt = slot ? (63 - a) : a;
    int s0 = qt << 4;

    short8 qf[8];
    #pragma unroll
    for (int kk = 0; kk < 8; ++kk)
        qf[kk] = *(const short8*)&Q[(((b << 10) + s0 + c) << 8) + kk * 32 + g * 8];

    float m = -1e30f, lsum = 0.f;
    f32x4 acc[16];
    #pragma unroll
    for (int i = 0; i < 16; ++i) acc[i] = (f32x4){0.f, 0.f, 0.f, 0.f};

    int tt = parity * 2;
    // ---- main loop: pairs of 16-wide t-subtiles (A = tt, B = tt+1) ----
    for (; tt + 1 <= qt; tt += 4) {
        int t0 = tt << 4;
        const unsigned short* Kp = &K[(((b << 10) + t0 + c) << 8)];
        f32x4 sA0 = {0,0,0,0}, sA1 = {0,0,0,0};
        f32x4 sB0 = {0,0,0,0}, sB1 = {0,0,0,0};
        __builtin_amdgcn_s_setprio(1);
        #pragma unroll
        for (int kk = 0; kk < 8; kk += 2) {
            short8 a0 = *(const short8*)&Kp[kk * 32 + g * 8];
            short8 a1 = *(const short8*)&Kp[(kk + 1) * 32 + g * 8];
            sA0 = __builtin_amdgcn_mfma_f32_16x16x32_bf16(a0, qf[kk], sA0, 0, 0, 0);
            sA1 = __builtin_amdgcn_mfma_f32_16x16x32_bf16(a1, qf[kk + 1], sA1, 0, 0, 0);
        }
        const unsigned short* Kp2 = Kp + (16 << 8);
        #pragma unroll
        for (int kk = 0; kk < 8; kk += 2) {
            short8 a0 = *(const short8*)&Kp2[kk * 32 + g * 8];
            short8 a1 = *(const short8*)&Kp2[(kk + 1) * 32 + g * 8];
            sB0 = __builtin_amdgcn_mfma_f32_16x16x32_bf16(a0, qf[kk], sB0, 0, 0, 0);
            sB1 = __builtin_amdgcn_mfma_f32_16x16x32_bf16(a1, qf[kk + 1], sB1, 0, 0, 0);
        }
        __builtin_amdgcn_s_setprio(0);
        // V loads issued before the softmax chain (latency hides under VALU)
        half4 vA[16], vB[16];
        #pragma unroll
        for (int vt = 0; vt < 16; ++vt)
            vA[vt] = *(const half4*)&V[(((b << 8) + vt * 16 + c) << 10) + t0 + 4 * g];
        #pragma unroll
        for (int vt = 0; vt < 16; ++vt)
            vB[vt] = *(const half4*)&V[(((b << 8) + vt * 16 + c) << 10) + t0 + 16 + 4 * g];

        float svA[4], svB[4];
        #pragma unroll
        for (int r = 0; r < 4; ++r) { svA[r] = (sA0[r] + sA1[r]) * 0.0625f;
                                      svB[r] = (sB0[r] + sB1[r]) * 0.0625f; }
        if (tt + 1 == qt) {   // subtile B is the diagonal tile
            #pragma unroll
            for (int r = 0; r < 4; ++r)
                if (4 * g + r > c) svB[r] = -1e30f;
        }
        float tm = fmaxf(fmaxf(fmaxf(svA[0], svA[1]), fmaxf(svA[2], svA[3])),
                         fmaxf(fmaxf(svB[0], svB[1]), fmaxf(svB[2], svB[3])));
        tm = fmaxf(tm, __shfl_xor(tm, 16));
        tm = fmaxf(tm, __shfl_xor(tm, 32));
        if (!__all((int)(tm <= m + 8.f))) {   // T13 defer-max
            float mnew = fmaxf(m, tm);
            float alpha = __expf(m - mnew);
            m = mnew;
            lsum *= alpha;
            #pragma unroll
            for (int i = 0; i < 16; ++i) acc[i] *= alpha;
        }
        float pA[4], pB[4], ps = 0.f;
        #pragma unroll
        for (int r = 0; r < 4; ++r) { pA[r] = __expf(svA[r] - m); ps += pA[r]; }
        #pragma unroll
        for (int r = 0; r < 4; ++r) { pB[r] = __expf(svB[r] - m); ps += pB[r]; }
        ps += __shfl_xor(ps, 16);
        ps += __shfl_xor(ps, 32);
        lsum += ps;
        half4 pbA, pbB;
        #pragma unroll
        for (int r = 0; r < 4; ++r) { pbA[r] = (_Float16)pA[r]; pbB[r] = (_Float16)pB[r]; }
        __builtin_amdgcn_s_setprio(1);
        #pragma unroll
        for (int vt = 0; vt < 16; ++vt)
            acc[vt] = __builtin_amdgcn_mfma_f32_16x16x16f16(vA[vt], pbA, acc[vt], 0, 0, 0);
        #pragma unroll
        for (int vt = 0; vt < 16; ++vt)
            acc[vt] = __builtin_amdgcn_mfma_f32_16x16x16f16(vB[vt], pbB, acc[vt], 0, 0, 0);
        __builtin_amdgcn_s_setprio(0);
    }
    // ---- tail: single diagonal subtile (tt == qt) ----
    if (tt <= qt) {
        int t0 = tt << 4;
        const unsigned short* Kp = &K[(((b << 10) + t0 + c) << 8)];
        f32x4 sA0 = {0,0,0,0}, sA1 = {0,0,0,0};
        #pragma unroll
        for (int kk = 0; kk < 8; kk += 2) {
            short8 a0 = *(const short8*)&Kp[kk * 32 + g * 8];
            short8 a1 = *(const short8*)&Kp[(kk + 1) * 32 + g * 8];
            sA0 = __builtin_amdgcn_mfma_f32_16x16x32_bf16(a0, qf[kk], sA0, 0, 0, 0);
            sA1 = __builtin_amdgcn_mfma_f32_16x16x32_bf16(a1, qf[kk + 1], sA1, 0, 0, 0);
        }
        half4 vA[16];
        #pragma unroll
        for (int vt = 0; vt < 16; ++vt)
            vA[vt] = *(const half4*)&V[(((b << 8) + vt * 16 + c) << 10) + t0 + 4 * g];
        float svA[4];
        #pragma unroll
        for (int r = 0; r < 4; ++r) {
            svA[r] = (sA0[r] + sA1[r]) * 0.0625f;
            if (4 * g + r > c) svA[r] = -1e30f;   // diagonal mask
        }
        float tm = fmaxf(fmaxf(svA[0], svA[1]), fmaxf(svA[2], svA[3]));
        tm = fmaxf(tm, __shfl_xor(tm, 16));
        tm = fmaxf(tm, __shfl_xor(tm, 32));
        if (!__all((int)(tm <= m + 8.f))) {
            float mnew = fmaxf(m, tm);
            float alpha = __expf(m - mnew);
            m = mnew;
            lsum *= alpha;
            #pragma unroll
            for (int i = 0; i < 16; ++i) acc[i] *= alpha;
        }
        float pA[4], ps = 0.f;
        #pragma unroll
        for (int r = 0; r < 4; ++r) { pA[r] = __expf(svA[r] - m); ps += pA[r]; }
        ps += __shfl_xor(ps, 16);
        ps += __shfl_xor(ps, 32);
        lsum += ps;
        half4 pbA;
        #pragma unroll
        for (int r = 0; r < 4; ++r) pbA[r] = (_Float16)pA[r];
        #pragma unroll
        for (int vt = 0; vt < 16; ++vt)
            acc[vt] = __builtin_amdgcn_mfma_f32_16x16x16f16(vA[vt], pbA, acc[vt], 0, 0, 0);
    }

    // ---- flash combine across the two parity waves of each slot ----
    if (parity == 0) {
        #pragma unroll
        for (int vt = 0; vt < 16; ++vt)
            *(f32x4*)&lacc[slot][c][vt * 16 + 4 * g] = acc[vt];
        if (g == 0) { lml[slot][0][c] = m; lml[slot][1][c] = lsum; }
    }
    __syncthreads();
    if (parity == 1) {
        float mA = lml[slot][0][c];
        float lA = lml[slot][1][c];
        float ms = fmaxf(mA, m);
        float aA = __expf(mA - ms);
        float aB = __expf(m - ms);
        float rl = 1.f / (lA * aA + lsum * aB);
        #pragma unroll
        for (int vt = 0; vt < 16; ++vt) {
            f32x4 other = *(const f32x4*)&lacc[slot][c][vt * 16 + 4 * g];
            #pragma unroll
            for (int r = 0; r < 4; ++r) {
                float val = (other[r] * aA + acc[vt][r] * aB) * rl;
                out[(((b << 8) + vt * 16 + 4 * g + r) << 10) + s0 + c] = val;
            }
        }
    }
}

// ---------- launcher ----------
extern "C" void kernel_launch(void* const* d_in, const int* in_sizes, int n_in,
                              void* d_out, int out_size, void* d_ws, size_t ws_size,
                              hipStream_t stream) {
    const float* x  = (const float*)d_in[0];
    const float* wq = (const float*)d_in[1];
    const float* bq = (const float*)d_in[2];
    const float* wk = (const float*)d_in[3];
    const float* bk = (const float*)d_in[4];
    const float* wv = (const float*)d_in[5];
    const float* bv = (const float*)d_in[6];
    float* out = (float*)d_out;

    char* ws = (char*)d_ws;
    unsigned short* Wb = (unsigned short*)ws;                       // 393,216 B
    unsigned short* X0 = (unsigned short*)(ws + 393216);            // 16,777,216 B
    unsigned short* Qb = (unsigned short*)(ws + 393216 + 16777216);
    unsigned short* Kb = (unsigned short*)(ws + 393216 + 2 * 16777216);
    _Float16*       Vb = (_Float16*)     (ws + 393216 + 3 * 16777216);

    wconv_kernel<<<768, 256, 0, stream>>>(wq, wk, wv, Wb);
    build_x0_kernel<<<dim3(32, 8, 32), 256, 0, stream>>>(x, X0);
    proj_kernel<<<dim3(16, 4, 96), 256, 0, stream>>>(X0, Wb, bq, bk, bv, Qb, Kb, Vb);
    attn_kernel<<<1024, 256, 0, stream>>>(Qb, Kb, Vb, out);
}

// Round 5
// 192.859 us; speedup vs baseline: 2.3225x; 1.6330x over previous
//
#include <hip/hip_runtime.h>
#include <cstdint>

typedef float  f32x4  __attribute__((ext_vector_type(4)));
typedef short  short8 __attribute__((ext_vector_type(8)));
typedef _Float16 half4 __attribute__((ext_vector_type(4)));

// ---------- helpers ----------
__device__ __forceinline__ unsigned short f2bf(float f) {
    unsigned u = __builtin_bit_cast(unsigned, f);
    u += 0x7FFFu + ((u >> 16) & 1u);   // RNE
    return (unsigned short)(u >> 16);
}

// ---------- kernel 1: weights fp32 -> bf16 (3 x 256 x 256) ----------
__global__ void wconv_kernel(const float* __restrict__ wq,
                             const float* __restrict__ wk,
                             const float* __restrict__ wv,
                             unsigned short* __restrict__ Wb) {
    int p = blockIdx.x >> 8;                       // 0..2
    int i = ((blockIdx.x & 255) << 8) + threadIdx.x; // 0..65535
    const float* src = (p == 0) ? wq : ((p == 1) ? wk : wv);
    Wb[(p << 16) + i] = f2bf(src[i]);
}

// ---------- kernel 2: build X0 [B][S][256] bf16 ----------
__global__ void build_x0_kernel(const float* __restrict__ x,
                                unsigned short* __restrict__ X0) {
    __shared__ float tile[32][33];
    int b  = blockIdx.z;
    int ct = blockIdx.y;     // 0..7  (32 channels each)
    int st = blockIdx.x;     // 0..31 (32 s each)
    int tid = threadIdx.x;
    int lo = tid & 31, hi = tid >> 5;   // 8 rows per pass

    if (ct < 7) {
        #pragma unroll
        for (int r = 0; r < 4; ++r) {
            int c = hi + 8 * r;
            tile[c][lo] = x[((b * 224 + ct * 32 + c) << 10) + st * 32 + lo];
        }
        __syncthreads();
        #pragma unroll
        for (int r = 0; r < 4; ++r) {
            int s_loc = hi + 8 * r;
            X0[(((b << 10) + st * 32 + s_loc) << 8) + ct * 32 + lo] = f2bf(tile[lo][s_loc]);
        }
    } else {
        #pragma unroll
        for (int r = 0; r < 4; ++r) {
            int s_loc = hi + 8 * r;
            int s = st * 32 + s_loc;
            int h = s >> 5, w = s & 31;
            int ch = lo;  // 0..31 -> pe channel
            int i = (ch < 16) ? (ch * 32 + h) : ((ch - 16) * 32 + w);
            int l = i >> 4, e = i & 15;
            float val = 0.f;
            if (l > 0) {
                float ang = (float)l * powf(10000.f, -(float)(e >> 1) * 0.125f);
                val = (e & 1) ? cosf(ang) : sinf(ang);
            }
            X0[(((b << 10) + s) << 8) + 224 + ch] = f2bf(val);
        }
    }
}

// ---------- kernel 3: QKV projection ----------
__global__ __launch_bounds__(256) void proj_kernel(
        const unsigned short* __restrict__ X0,
        const unsigned short* __restrict__ Wb,
        const float* __restrict__ bq, const float* __restrict__ bk,
        const float* __restrict__ bv,
        unsigned short* __restrict__ Q, unsigned short* __restrict__ K,
        _Float16* __restrict__ V) {
    int pb = blockIdx.z; int proj = pb >> 5; int b = pb & 31;
    int tid = threadIdx.x; int w = tid >> 6; int l = tid & 63;
    int g = l >> 4, c = l & 15;
    int s0 = blockIdx.x * 64 + w * 16;
    int o0 = blockIdx.y * 64;
    const unsigned short* Wp = Wb + (proj << 16);
    const float* bias = (proj == 0) ? bq : ((proj == 1) ? bk : bv);

    f32x4 acc[4];
    #pragma unroll
    for (int ot = 0; ot < 4; ++ot) acc[ot] = (f32x4){0.f, 0.f, 0.f, 0.f};

    const short8* arow = (const short8*)&X0[(((b << 10) + s0 + c) << 8)];
    #pragma unroll
    for (int kk = 0; kk < 8; ++kk) {
        short8 a = arow[kk * 4 + g];     // d = kk*32 + 8g .. +7
        #pragma unroll
        for (int ot = 0; ot < 4; ++ot) {
            short8 bfr = *(const short8*)&Wp[(o0 + ot * 16 + c) * 256 + kk * 32 + g * 8];
            acc[ot] = __builtin_amdgcn_mfma_f32_16x16x32_bf16(a, bfr, acc[ot], 0, 0, 0);
        }
    }

    #pragma unroll
    for (int ot = 0; ot < 4; ++ot) {
        int o = o0 + ot * 16 + c;
        float bb = bias[o];
        if (proj < 2) {
            unsigned short* dst = (proj == 0) ? Q : K;
            #pragma unroll
            for (int r = 0; r < 4; ++r) {
                float v = fmaxf(acc[ot][r] + bb, 0.f);
                int s = s0 + 4 * g + r;
                dst[(((b << 10) + s) << 8) + o] = f2bf(v);
            }
        } else {
            half4 hv;
            #pragma unroll
            for (int r = 0; r < 4; ++r)
                hv[r] = (_Float16)fmaxf(acc[ot][r] + bb, 0.f);
            *(half4*)&V[(((b << 8) + o) << 10) + s0 + 4 * g] = hv;
        }
    }
}

// ---------- kernel 4: causal attention, LDS-staged K/V tiles ----------
// 512 blocks x 256 threads. Block = (batch XCD-grouped, 64-row q-tile).
// 4 waves x 16 q-rows. Per t-tile (64): stage K (32KB) + V (32KB) into
// swizzled LDS with coalesced loads, then all waves read fragments from LDS.
// bid bits: [8]=half [7:6]=bhi [5:3]=qv [2:0]=xcd ; qt = half? qv : 15-qv
// -> blocks bid and bid+256 (co-resident pair) have qt+qt' = 15 (balance),
//    long tiles dispatched first.
__global__ __launch_bounds__(256, 2) void attn_kernel(
        const unsigned short* __restrict__ Q,
        const unsigned short* __restrict__ K,
        const _Float16* __restrict__ V,
        float* __restrict__ out) {
    __shared__ __align__(16) char Klds[32768];   // 64 t-rows x 512B, 16B chunks XOR (row&7)
    __shared__ __align__(16) char Vlds[32768];   // 256 v-rows x 128B, 16B chunks XOR (v&7)

    int bid = blockIdx.x;
    int xcd  = bid & 7;
    int qv   = (bid >> 3) & 7;
    int bhi  = (bid >> 6) & 3;
    int half = bid >> 8;
    int b  = (bhi << 3) | xcd;
    int qt = half ? qv : (15 - qv);
    int sbase = qt << 6;

    int tid = threadIdx.x; int w = tid >> 6; int l = tid & 63;
    int g = l >> 4, c = l & 15;
    int s0 = sbase + (w << 4);          // this wave's 16 q-rows

    short8 qf[8];
    #pragma unroll
    for (int kk = 0; kk < 8; ++kk)
        qf[kk] = *(const short8*)&Q[(((b << 10) + s0 + c) << 8) + kk * 32 + g * 8];

    float m = -1e30f, lsum = 0.f;
    f32x4 acc[16];
    #pragma unroll
    for (int i = 0; i < 16; ++i) acc[i] = (f32x4){0.f, 0.f, 0.f, 0.f};

    int ntiles = qt + 1;
    for (int t = 0; t < ntiles; ++t) {
        int t0 = t << 6;
        if (t) __syncthreads();          // previous tile fully consumed
        // ---- stage K tile: 2048 16B chunks, 8 per thread, coalesced ----
        const unsigned short* Kg = &K[((b << 10) + t0) << 8];
        #pragma unroll
        for (int p = 0; p < 8; ++p) {
            int ch = p * 256 + tid;
            int trow = ch >> 5, cc = ch & 31;
            short8 kv = *(const short8*)&Kg[(trow << 8) + cc * 8];
            *(short8*)&Klds[((ch & ~31) | (cc ^ (trow & 7))) << 4] = kv;
        }
        // ---- stage V tile: 2048 16B chunks (256 v-rows x 128B) ----
        const _Float16* Vg = &V[((b << 8) << 10) + t0];
        #pragma unroll
        for (int p = 0; p < 8; ++p) {
            int ch = p * 256 + tid;
            int v = ch >> 3, gg = ch & 7;
            short8 vv = *(const short8*)&Vg[(v << 10) + gg * 8];
            *(short8*)&Vlds[((ch & ~7) | (gg ^ (v & 7))) << 4] = vv;
        }
        __syncthreads();

        bool diag = (t == qt);
        int nsub = diag ? (w + 1) : 4;
        for (int sub = 0; sub < nsub; ++sub) {
            int toff = sub << 4;
            // ---- QK^T from LDS ----
            f32x4 sc0 = {0.f,0.f,0.f,0.f}, sc1 = {0.f,0.f,0.f,0.f};
            const char* kbase = &Klds[(toff + c) * 512];
            __builtin_amdgcn_s_setprio(1);
            #pragma unroll
            for (int kk = 0; kk < 8; kk += 2) {
                short8 a0 = *(const short8*)&kbase[(((kk * 4 + g)     ^ (c & 7)) << 4)];
                short8 a1 = *(const short8*)&kbase[((((kk + 1) * 4 + g) ^ (c & 7)) << 4)];
                sc0 = __builtin_amdgcn_mfma_f32_16x16x32_bf16(a0, qf[kk], sc0, 0, 0, 0);
                sc1 = __builtin_amdgcn_mfma_f32_16x16x32_bf16(a1, qf[kk + 1], sc1, 0, 0, 0);
            }
            __builtin_amdgcn_s_setprio(0);
            // ---- V fragments from LDS (issued before softmax chain) ----
            half4 vf[16];
            int chv = ((toff >> 3) + (g >> 1));
            #pragma unroll
            for (int vt = 0; vt < 16; ++vt)
                vf[vt] = *(const half4*)&Vlds[(vt * 16 + c) * 128 +
                                              ((chv ^ (c & 7)) << 4) + (g & 1) * 8];
            // ---- online softmax (T13 defer-max) ----
            float sv[4];
            #pragma unroll
            for (int r = 0; r < 4; ++r) sv[r] = (sc0[r] + sc1[r]) * 0.0625f;
            if (diag && sub == w) {
                #pragma unroll
                for (int r = 0; r < 4; ++r)
                    if (4 * g + r > c) sv[r] = -1e30f;
            }
            float tm = fmaxf(fmaxf(sv[0], sv[1]), fmaxf(sv[2], sv[3]));
            tm = fmaxf(tm, __shfl_xor(tm, 16));
            tm = fmaxf(tm, __shfl_xor(tm, 32));
            if (!__all((int)(tm <= m + 8.f))) {
                float mnew = fmaxf(m, tm);
                float alpha = __expf(m - mnew);
                m = mnew;
                lsum *= alpha;
                #pragma unroll
                for (int i = 0; i < 16; ++i) acc[i] *= alpha;
            }
            float p[4], ps = 0.f;
            #pragma unroll
            for (int r = 0; r < 4; ++r) { p[r] = __expf(sv[r] - m); ps += p[r]; }
            ps += __shfl_xor(ps, 16);
            ps += __shfl_xor(ps, 32);
            lsum += ps;
            half4 pb;
            #pragma unroll
            for (int r = 0; r < 4; ++r) pb[r] = (_Float16)p[r];
            // ---- PV ----
            __builtin_amdgcn_s_setprio(1);
            #pragma unroll
            for (int vt = 0; vt < 16; ++vt)
                acc[vt] = __builtin_amdgcn_mfma_f32_16x16x16f16(vf[vt], pb, acc[vt], 0, 0, 0);
            __builtin_amdgcn_s_setprio(0);
        }
    }

    float rl = 1.f / lsum;
    #pragma unroll
    for (int vt = 0; vt < 16; ++vt) {
        #pragma unroll
        for (int r = 0; r < 4; ++r)
            out[(((b << 8) + vt * 16 + 4 * g + r) << 10) + s0 + c] = acc[vt][r] * rl;
    }
}

// ---------- launcher ----------
extern "C" void kernel_launch(void* const* d_in, const int* in_sizes, int n_in,
                              void* d_out, int out_size, void* d_ws, size_t ws_size,
                              hipStream_t stream) {
    const float* x  = (const float*)d_in[0];
    const float* wq = (const float*)d_in[1];
    const float* bq = (const float*)d_in[2];
    const float* wk = (const float*)d_in[3];
    const float* bk = (const float*)d_in[4];
    const float* wv = (const float*)d_in[5];
    const float* bv = (const float*)d_in[6];
    float* out = (float*)d_out;

    char* ws = (char*)d_ws;
    unsigned short* Wb = (unsigned short*)ws;                       // 393,216 B
    unsigned short* X0 = (unsigned short*)(ws + 393216);            // 16,777,216 B
    unsigned short* Qb = (unsigned short*)(ws + 393216 + 16777216);
    unsigned short* Kb = (unsigned short*)(ws + 393216 + 2 * 16777216);
    _Float16*       Vb = (_Float16*)     (ws + 393216 + 3 * 16777216);

    wconv_kernel<<<768, 256, 0, stream>>>(wq, wk, wv, Wb);
    build_x0_kernel<<<dim3(32, 8, 32), 256, 0, stream>>>(x, X0);
    proj_kernel<<<dim3(16, 4, 96), 256, 0, stream>>>(X0, Wb, bq, bk, bv, Qb, Kb, Vb);
    attn_kernel<<<512, 256, 0, stream>>>(Qb, Kb, Vb, out);
}

// Round 6
// 122.463 us; speedup vs baseline: 3.6576x; 1.5748x over previous
//
#include <hip/hip_runtime.h>
#include <cstdint>

typedef float  f32x4  __attribute__((ext_vector_type(4)));
typedef short  short8 __attribute__((ext_vector_type(8)));
typedef _Float16 half4 __attribute__((ext_vector_type(4)));

// ---------- helpers ----------
__device__ __forceinline__ unsigned short f2bf(float f) {
    unsigned u = __builtin_bit_cast(unsigned, f);
    u += 0x7FFFu + ((u >> 16) & 1u);   // RNE
    return (unsigned short)(u >> 16);
}

// ---------- kernel 1: weights fp32 -> bf16 (3 x 256 x 256) ----------
__global__ void wconv_kernel(const float* __restrict__ wq,
                             const float* __restrict__ wk,
                             const float* __restrict__ wv,
                             unsigned short* __restrict__ Wb) {
    int p = blockIdx.x >> 8;                       // 0..2
    int i = ((blockIdx.x & 255) << 8) + threadIdx.x; // 0..65535
    const float* src = (p == 0) ? wq : ((p == 1) ? wk : wv);
    Wb[(p << 16) + i] = f2bf(src[i]);
}

// ---------- kernel 2: build X0 [B][S][256] bf16 ----------
__global__ void build_x0_kernel(const float* __restrict__ x,
                                unsigned short* __restrict__ X0) {
    __shared__ float tile[32][33];
    int b  = blockIdx.z;
    int ct = blockIdx.y;     // 0..7  (32 channels each)
    int st = blockIdx.x;     // 0..31 (32 s each)
    int tid = threadIdx.x;
    int lo = tid & 31, hi = tid >> 5;   // 8 rows per pass

    if (ct < 7) {
        #pragma unroll
        for (int r = 0; r < 4; ++r) {
            int c = hi + 8 * r;
            tile[c][lo] = x[((b * 224 + ct * 32 + c) << 10) + st * 32 + lo];
        }
        __syncthreads();
        #pragma unroll
        for (int r = 0; r < 4; ++r) {
            int s_loc = hi + 8 * r;
            X0[(((b << 10) + st * 32 + s_loc) << 8) + ct * 32 + lo] = f2bf(tile[lo][s_loc]);
        }
    } else {
        #pragma unroll
        for (int r = 0; r < 4; ++r) {
            int s_loc = hi + 8 * r;
            int s = st * 32 + s_loc;
            int h = s >> 5, w = s & 31;
            int ch = lo;  // 0..31 -> pe channel
            int i = (ch < 16) ? (ch * 32 + h) : ((ch - 16) * 32 + w);
            int l = i >> 4, e = i & 15;
            float val = 0.f;
            if (l > 0) {
                float ang = (float)l * powf(10000.f, -(float)(e >> 1) * 0.125f);
                val = (e & 1) ? cosf(ang) : sinf(ang);
            }
            X0[(((b << 10) + s) << 8) + 224 + ch] = f2bf(val);
        }
    }
}

// ---------- kernel 3: QKV projection, LDS-staged ----------
// Block = (proj, b, 64-s tile, 64-o tile), 256 threads (4 waves).
// Stage X0 tile [64s][256c] and W tile [64o][256c] in XOR-swizzled LDS
// (16B chunk index ^ (row&7)); all MFMA fragments read from LDS.
__global__ __launch_bounds__(256) void proj_kernel(
        const unsigned short* __restrict__ X0,
        const unsigned short* __restrict__ Wb,
        const float* __restrict__ bq, const float* __restrict__ bk,
        const float* __restrict__ bv,
        unsigned short* __restrict__ Q, unsigned short* __restrict__ K,
        _Float16* __restrict__ V) {
    __shared__ __align__(16) char Xlds[32768];   // 64 s-rows x 512B
    __shared__ __align__(16) char Wlds[32768];   // 64 o-rows x 512B

    int pb = blockIdx.z; int proj = pb >> 5; int b = pb & 31;
    int tid = threadIdx.x; int w = tid >> 6; int l = tid & 63;
    int g = l >> 4, c = l & 15;
    int sb = blockIdx.x * 64;           // s-tile base
    int o0 = blockIdx.y * 64;           // o-tile base
    const unsigned short* Wp = Wb + (proj << 16);
    const float* bias = (proj == 0) ? bq : ((proj == 1) ? bk : bv);

    // ---- stage X0 tile: 2048 16B chunks, coalesced, swizzled ----
    const unsigned short* Xg = &X0[((b << 10) + sb) << 8];
    #pragma unroll
    for (int p = 0; p < 8; ++p) {
        int ch = p * 256 + tid;
        int row = ch >> 5, cc = ch & 31;
        short8 v = *(const short8*)&Xg[(row << 8) + cc * 8];
        *(short8*)&Xlds[((ch & ~31) | (cc ^ (row & 7))) << 4] = v;
    }
    // ---- stage W tile: 2048 16B chunks ----
    const unsigned short* Wg = &Wp[o0 << 8];
    #pragma unroll
    for (int p = 0; p < 8; ++p) {
        int ch = p * 256 + tid;
        int row = ch >> 5, cc = ch & 31;
        short8 v = *(const short8*)&Wg[(row << 8) + cc * 8];
        *(short8*)&Wlds[((ch & ~31) | (cc ^ (row & 7))) << 4] = v;
    }
    __syncthreads();

    // ---- A fragments (this wave's 16 s-rows) into registers ----
    int s0 = sb + w * 16;
    const char* abase = &Xlds[(w * 16 + c) * 512];
    short8 af[8];
    #pragma unroll
    for (int kk = 0; kk < 8; ++kk)
        af[kk] = *(const short8*)&abase[((kk * 4 + g) ^ (c & 7)) << 4];

    f32x4 acc[4];
    #pragma unroll
    for (int ot = 0; ot < 4; ++ot) acc[ot] = (f32x4){0.f, 0.f, 0.f, 0.f};

    __builtin_amdgcn_s_setprio(1);
    #pragma unroll
    for (int ot = 0; ot < 4; ++ot) {
        const char* bbase = &Wlds[(ot * 16 + c) * 512];
        #pragma unroll
        for (int kk = 0; kk < 8; ++kk) {
            short8 bfr = *(const short8*)&bbase[((kk * 4 + g) ^ (c & 7)) << 4];
            acc[ot] = __builtin_amdgcn_mfma_f32_16x16x32_bf16(af[kk], bfr, acc[ot], 0, 0, 0);
        }
    }
    __builtin_amdgcn_s_setprio(0);

    #pragma unroll
    for (int ot = 0; ot < 4; ++ot) {
        int o = o0 + ot * 16 + c;
        float bb = bias[o];
        if (proj < 2) {
            unsigned short* dst = (proj == 0) ? Q : K;
            #pragma unroll
            for (int r = 0; r < 4; ++r) {
                float v = fmaxf(acc[ot][r] + bb, 0.f);
                int s = s0 + 4 * g + r;
                dst[(((b << 10) + s) << 8) + o] = f2bf(v);
            }
        } else {
            half4 hv;
            #pragma unroll
            for (int r = 0; r < 4; ++r)
                hv[r] = (_Float16)fmaxf(acc[ot][r] + bb, 0.f);
            *(half4*)&V[(((b << 8) + o) << 10) + s0 + 4 * g] = hv;
        }
    }
}

// ---------- kernel 4: causal attention, LDS-staged K/V tiles ----------
// 512 blocks x 256 threads. Block = (batch XCD-grouped, 64-row q-tile).
// 4 waves x 16 q-rows. Per t-tile (64): stage K (32KB) + V (32KB) into
// swizzled LDS with coalesced loads, then all waves read fragments from LDS.
__global__ __launch_bounds__(256, 2) void attn_kernel(
        const unsigned short* __restrict__ Q,
        const unsigned short* __restrict__ K,
        const _Float16* __restrict__ V,
        float* __restrict__ out) {
    __shared__ __align__(16) char Klds[32768];   // 64 t-rows x 512B, 16B chunks XOR (row&7)
    __shared__ __align__(16) char Vlds[32768];   // 256 v-rows x 128B, 16B chunks XOR (v&7)

    int bid = blockIdx.x;
    int xcd  = bid & 7;
    int qv   = (bid >> 3) & 7;
    int bhi  = (bid >> 6) & 3;
    int half = bid >> 8;
    int b  = (bhi << 3) | xcd;
    int qt = half ? qv : (15 - qv);
    int sbase = qt << 6;

    int tid = threadIdx.x; int w = tid >> 6; int l = tid & 63;
    int g = l >> 4, c = l & 15;
    int s0 = sbase + (w << 4);          // this wave's 16 q-rows

    short8 qf[8];
    #pragma unroll
    for (int kk = 0; kk < 8; ++kk)
        qf[kk] = *(const short8*)&Q[(((b << 10) + s0 + c) << 8) + kk * 32 + g * 8];

    float m = -1e30f, lsum = 0.f;
    f32x4 acc[16];
    #pragma unroll
    for (int i = 0; i < 16; ++i) acc[i] = (f32x4){0.f, 0.f, 0.f, 0.f};

    int ntiles = qt + 1;
    for (int t = 0; t < ntiles; ++t) {
        int t0 = t << 6;
        if (t) __syncthreads();          // previous tile fully consumed
        // ---- stage K tile: 2048 16B chunks, 8 per thread, coalesced ----
        const unsigned short* Kg = &K[((b << 10) + t0) << 8];
        #pragma unroll
        for (int p = 0; p < 8; ++p) {
            int ch = p * 256 + tid;
            int trow = ch >> 5, cc = ch & 31;
            short8 kv = *(const short8*)&Kg[(trow << 8) + cc * 8];
            *(short8*)&Klds[((ch & ~31) | (cc ^ (trow & 7))) << 4] = kv;
        }
        // ---- stage V tile: 2048 16B chunks (256 v-rows x 128B) ----
        const _Float16* Vg = &V[((b << 8) << 10) + t0];
        #pragma unroll
        for (int p = 0; p < 8; ++p) {
            int ch = p * 256 + tid;
            int v = ch >> 3, gg = ch & 7;
            short8 vv = *(const short8*)&Vg[(v << 10) + gg * 8];
            *(short8*)&Vlds[((ch & ~7) | (gg ^ (v & 7))) << 4] = vv;
        }
        __syncthreads();

        bool diag = (t == qt);
        int nsub = diag ? (w + 1) : 4;
        for (int sub = 0; sub < nsub; ++sub) {
            int toff = sub << 4;
            // ---- QK^T from LDS ----
            f32x4 sc0 = {0.f,0.f,0.f,0.f}, sc1 = {0.f,0.f,0.f,0.f};
            const char* kbase = &Klds[(toff + c) * 512];
            __builtin_amdgcn_s_setprio(1);
            #pragma unroll
            for (int kk = 0; kk < 8; kk += 2) {
                short8 a0 = *(const short8*)&kbase[(((kk * 4 + g)     ^ (c & 7)) << 4)];
                short8 a1 = *(const short8*)&kbase[((((kk + 1) * 4 + g) ^ (c & 7)) << 4)];
                sc0 = __builtin_amdgcn_mfma_f32_16x16x32_bf16(a0, qf[kk], sc0, 0, 0, 0);
                sc1 = __builtin_amdgcn_mfma_f32_16x16x32_bf16(a1, qf[kk + 1], sc1, 0, 0, 0);
            }
            __builtin_amdgcn_s_setprio(0);
            // ---- V fragments from LDS (issued before softmax chain) ----
            half4 vf[16];
            int chv = ((toff >> 3) + (g >> 1));
            #pragma unroll
            for (int vt = 0; vt < 16; ++vt)
                vf[vt] = *(const half4*)&Vlds[(vt * 16 + c) * 128 +
                                              ((chv ^ (c & 7)) << 4) + (g & 1) * 8];
            // ---- online softmax (T13 defer-max) ----
            float sv[4];
            #pragma unroll
            for (int r = 0; r < 4; ++r) sv[r] = (sc0[r] + sc1[r]) * 0.0625f;
            if (diag && sub == w) {
                #pragma unroll
                for (int r = 0; r < 4; ++r)
                    if (4 * g + r > c) sv[r] = -1e30f;
            }
            float tm = fmaxf(fmaxf(sv[0], sv[1]), fmaxf(sv[2], sv[3]));
            tm = fmaxf(tm, __shfl_xor(tm, 16));
            tm = fmaxf(tm, __shfl_xor(tm, 32));
            if (!__all((int)(tm <= m + 8.f))) {
                float mnew = fmaxf(m, tm);
                float alpha = __expf(m - mnew);
                m = mnew;
                lsum *= alpha;
                #pragma unroll
                for (int i = 0; i < 16; ++i) acc[i] *= alpha;
            }
            float p[4], ps = 0.f;
            #pragma unroll
            for (int r = 0; r < 4; ++r) { p[r] = __expf(sv[r] - m); ps += p[r]; }
            ps += __shfl_xor(ps, 16);
            ps += __shfl_xor(ps, 32);
            lsum += ps;
            half4 pb;
            #pragma unroll
            for (int r = 0; r < 4; ++r) pb[r] = (_Float16)p[r];
            // ---- PV ----
            __builtin_amdgcn_s_setprio(1);
            #pragma unroll
            for (int vt = 0; vt < 16; ++vt)
                acc[vt] = __builtin_amdgcn_mfma_f32_16x16x16f16(vf[vt], pb, acc[vt], 0, 0, 0);
            __builtin_amdgcn_s_setprio(0);
        }
    }

    float rl = 1.f / lsum;
    #pragma unroll
    for (int vt = 0; vt < 16; ++vt) {
        #pragma unroll
        for (int r = 0; r < 4; ++r)
            out[(((b << 8) + vt * 16 + 4 * g + r) << 10) + s0 + c] = acc[vt][r] * rl;
    }
}

// ---------- launcher ----------
extern "C" void kernel_launch(void* const* d_in, const int* in_sizes, int n_in,
                              void* d_out, int out_size, void* d_ws, size_t ws_size,
                              hipStream_t stream) {
    const float* x  = (const float*)d_in[0];
    const float* wq = (const float*)d_in[1];
    const float* bq = (const float*)d_in[2];
    const float* wk = (const float*)d_in[3];
    const float* bk = (const float*)d_in[4];
    const float* wv = (const float*)d_in[5];
    const float* bv = (const float*)d_in[6];
    float* out = (float*)d_out;

    char* ws = (char*)d_ws;
    unsigned short* Wb = (unsigned short*)ws;                       // 393,216 B
    unsigned short* X0 = (unsigned short*)(ws + 393216);            // 16,777,216 B
    unsigned short* Qb = (unsigned short*)(ws + 393216 + 16777216);
    unsigned short* Kb = (unsigned short*)(ws + 393216 + 2 * 16777216);
    _Float16*       Vb = (_Float16*)     (ws + 393216 + 3 * 16777216);

    wconv_kernel<<<768, 256, 0, stream>>>(wq, wk, wv, Wb);
    build_x0_kernel<<<dim3(32, 8, 32), 256, 0, stream>>>(x, X0);
    proj_kernel<<<dim3(16, 4, 96), 256, 0, stream>>>(X0, Wb, bq, bk, bv, Qb, Kb, Vb);
    attn_kernel<<<512, 256, 0, stream>>>(Qb, Kb, Vb, out);
}